// Round 14
// baseline (281.861 us; speedup 1.0000x reference)
//
#include <hip/hip_runtime.h>
#include <hip/hip_bf16.h>
#include <math.h>

#define NUM_CLUSTERS 16
#define HIDDEN 1024
#define BOT 128
#define NTOK 65536

typedef __attribute__((ext_vector_type(8))) short bf16x8;
typedef __attribute__((ext_vector_type(4))) short bf16x4;
typedef __attribute__((ext_vector_type(4))) float f32x4;

typedef __attribute__((address_space(3))) unsigned int lds_u32;
typedef const __attribute__((address_space(1))) unsigned int glb_u32;

__device__ __forceinline__ void gload16(const void* g, void* l) {
  __builtin_amdgcn_global_load_lds((glb_u32*)g, (lds_u32*)l, 16, 0, 0);
}

__device__ __forceinline__ unsigned short f2bf(float x) {
  union { float f; unsigned u; } v; v.f = x;
  unsigned r = v.u + 0x7fffu + ((v.u >> 16) & 1u);
  return (unsigned short)(r >> 16);
}

__device__ __forceinline__ bf16x4 pack4(float4 a) {
  bf16x4 r;
  r[0] = (short)f2bf(a.x); r[1] = (short)f2bf(a.y);
  r[2] = (short)f2bf(a.z); r[3] = (short)f2bf(a.w);
  return r;
}

__device__ __forceinline__ bf16x8 pack8(float4 a, float4 b) {
  bf16x8 r;
  r[0] = (short)f2bf(a.x); r[1] = (short)f2bf(a.y);
  r[2] = (short)f2bf(a.z); r[3] = (short)f2bf(a.w);
  r[4] = (short)f2bf(b.x); r[5] = (short)f2bf(b.y);
  r[6] = (short)f2bf(b.z); r[7] = (short)f2bf(b.w);
  return r;
}

// short-index swizzle: XOR short-idx bits 3..5 with (row&7) -> 16B-chunk spread
#define SWZS(row, sidx) ((sidx) ^ (((row) & 7) << 3))

#define SCB() __builtin_amdgcn_sched_barrier(0)
#define VMW(n)                                          \
  do {                                                  \
    SCB();                                              \
    asm volatile("s_waitcnt vmcnt(" #n ")" ::: "memory"); \
    SCB();                                              \
  } while (0)
#define SBAR()                                  \
  do {                                          \
    SCB();                                      \
    __builtin_amdgcn_s_barrier();               \
    SCB();                                      \
  } while (0)
#define LGKM0() asm volatile("s_waitcnt lgkmcnt(0)" ::: "memory")

// bijective XCD-chunk swizzle (m204)
__device__ __forceinline__ int xcd_swz(int bid, int nwg) {
  const int nx = 8;
  int q = nwg / nx, r = nwg % nx;
  int xcd = bid % nx, idx = bid / nx;
  int b = (xcd < r) ? xcd * (q + 1) : r * (q + 1) + (xcd - r) * q;
  return b + idx;
}

// ---------------- prep kernels ----------------

__global__ void k_zero(int* p) {
  if (threadIdx.x < 64) p[threadIdx.x] = 0;
}

__global__ void k_hist(const int* __restrict__ ids, int* __restrict__ counts) {
  __shared__ int lh[NUM_CLUSTERS];
  if (threadIdx.x < NUM_CLUSTERS) lh[threadIdx.x] = 0;
  __syncthreads();
  int i = blockIdx.x * blockDim.x + threadIdx.x;
  int stride = gridDim.x * blockDim.x;
  for (; i < NTOK; i += stride) atomicAdd(&lh[ids[i]], 1);
  __syncthreads();
  if (threadIdx.x < NUM_CLUSTERS) atomicAdd(&counts[threadIdx.x], lh[threadIdx.x]);
}

__global__ void k_scan(const int* __restrict__ counts, int* __restrict__ offsets,
                       int* __restrict__ cursor) {
  if (threadIdx.x == 0 && blockIdx.x == 0) {
    int s = 0;
    for (int c = 0; c < NUM_CLUSTERS; ++c) {
      offsets[c] = s; cursor[c] = s; s += counts[c];
    }
    offsets[NUM_CLUSTERS] = s;
  }
}

__global__ void k_scatter(const int* __restrict__ ids, int* cursor,
                          int* __restrict__ perm) {
  __shared__ int lh[NUM_CLUSTERS], lbase[NUM_CLUSTERS];
  const int tid = threadIdx.x;
  if (tid < NUM_CLUSTERS) lh[tid] = 0;
  __syncthreads();
  const int i = blockIdx.x * 256 + tid;
  const int cc = ids[i];
  const int r = atomicAdd(&lh[cc], 1);
  __syncthreads();
  if (tid < NUM_CLUSTERS) lbase[tid] = atomicAdd(&cursor[tid], lh[tid]);
  __syncthreads();
  perm[lbase[cc] + r] = i;
}

// MAIN path: W1 [16][1024][128] -> per-(c,ks32) 8KB images of W1^T [n=128][k=32].
// FORWARD map (fixes R13 OOB/inversion bug): logical (n, lg) stores its 16B
// fragment at phys byte ((n*64 + lg*16) ^ ((n&7)<<4)) — exactly the kernel's
// read formula SWZS(n, n*32 + lg*8) in bytes. Bijective by construction.
__global__ void k_w1til32(const float* __restrict__ W1, unsigned short* __restrict__ outw) {
  const int id = blockIdx.x * 256 + threadIdx.x;   // 262144 total
  const int c   = id >> 14;
  const int rem = id & 16383;          // ks(5) | n(7) | lg(2)
  const int ks  = rem >> 9;
  const int n   = (rem >> 2) & 127;
  const int lg  = rem & 3;
  const int k0  = ks * 32 + lg * 8;    // <= 1023, in-bounds
  const float* src = W1 + ((size_t)c * HIDDEN + k0) * BOT + n;
  unsigned short v[8];
  #pragma unroll
  for (int j = 0; j < 8; ++j) v[j] = f2bf(src[(size_t)j * BOT]);
  const int phys = (n * 64 + lg * 16) ^ ((n & 7) << 4);   // byte offset in 8KB image
  *(uint4*)((char*)outw + ((size_t)(c * 32 + ks)) * 8192 + phys) = *(const uint4*)v;
}

// MAIN path: W2 [16][128][1024] -> fragment-linear 32-col-chunk layout:
// outw[((c*256 + nc*8 + kk*2 + nf)*64 + l)*8 + i] =
//   bf16(W2[c][kk*32 + (l>>4)*8 + i][nc*32 + nf*16 + (l&15)])
__global__ void k_w2lin32(const float* __restrict__ W2, unsigned short* __restrict__ outw) {
  const int id = blockIdx.x * 256 + threadIdx.x;   // 262144 total
  const int c   = id >> 14;
  const int fg  = (id >> 6) & 255;     // nc*8 + kk*2 + nf
  const int l   = id & 63;
  const int nc  = fg >> 3, kk = (fg >> 1) & 3, nf = fg & 1;
  const int n   = nc * 32 + nf * 16 + (l & 15);
  const int k0  = kk * 32 + (l >> 4) * 8;
  const float* src = W2 + ((size_t)c * BOT + k0) * HIDDEN + n;
  unsigned short v[8];
  #pragma unroll
  for (int j = 0; j < 8; ++j) v[j] = f2bf(src[(size_t)j * HIDDEN]);
  *(uint4*)(outw + (size_t)id * 8) = *(const uint4*)v;
}

// FALLBACK path preps (old layouts, unchanged)
__global__ void k_w1til(const float* __restrict__ W1, unsigned short* __restrict__ outw) {
  const int id = blockIdx.x * 256 + threadIdx.x;
  const int c  = id >> 14;
  const int ks = (id >> 10) & 15;
  const int q  = id & 1023;
  const int o  = q << 4;
  const int row = o >> 7;
  const int lb  = (o & 127) ^ ((row & 7) << 4);
  const int k0  = ks * 64 + (lb >> 1);
  const float* src = W1 + ((size_t)c * HIDDEN + k0) * BOT + row;
  unsigned short v[8];
  #pragma unroll
  for (int j = 0; j < 8; ++j) v[j] = f2bf(src[(size_t)j * BOT]);
  *(uint4*)((char*)outw + ((size_t)(c * 16 + ks)) * 16384 + o) = *(const uint4*)v;
}

__global__ void k_w2til(const float* __restrict__ W2, unsigned short* __restrict__ outw) {
  const int id = blockIdx.x * 256 + threadIdx.x;
  const int c  = id >> 14;
  const int nc = (id >> 10) & 15;
  const int q  = id & 1023;
  const int o  = q << 4;
  const int row = o >> 8;
  const int lb  = (o & 255) ^ ((row & 7) << 4);
  const int b0  = lb >> 1;
  const int n   = nc * 64 + row;
  const float* src = W2 + ((size_t)c * BOT + b0) * HIDDEN + n;
  unsigned short v[8];
  #pragma unroll
  for (int j = 0; j < 8; ++j) v[j] = f2bf(src[(size_t)j * HIDDEN]);
  *(uint4*)((char*)outw + ((size_t)(c * 16 + nc)) * 16384 + o) = *(const uint4*)v;
}

// ---- common tile locator: TM tokens per tile ----
__device__ __forceinline__ bool locate(const int* offsets, int bid, int TMv,
                                       int& c, int& base, int& nvalid) {
  int t = bid;
  for (c = 0; c < NUM_CLUSTERS; ++c) {
    int cnt = offsets[c + 1] - offsets[c];
    int nt = (cnt + TMv - 1) / TMv;
    if (t < nt) {
      base = offsets[c] + t * TMv;
      nvalid = min(TMv, offsets[c + 1] - base);
      return true;
    }
    t -= nt;
  }
  return false;
}

// ---------------- FUSED kernel, 32KB LDS / 4 blocks/CU / 32 waves/CU --------
// Phase 1: BK=32, 32 K-steps, counted vmcnt, 1 barrier/step.
//   LDS: sA dbuf 2x4KB [0,8K), sB1 dbuf 2x8KB [8K,24K).
// Phase 2: 32 chunks x 32 cols, counted vmcnt, 1 barrier/chunk.
//   LDS: sMid 16KB [0,16K), sB2 dbuf 2x8KB [16K,32K).

__global__ __launch_bounds__(512, 8) void k_fuse(
    const float* __restrict__ h, const float* __restrict__ b1g,
    const float* __restrict__ b2g, const unsigned short* __restrict__ W1til,
    const unsigned short* __restrict__ W2lin, const int* __restrict__ offsets,
    const int* __restrict__ perm, float* __restrict__ out) {

  __shared__ __align__(16) unsigned char sLds[32768];
  __shared__ int sTok[64];

#define SA(cur)  ((unsigned short*)(sLds + (cur) * 4096))
#define SB1(cur) ((unsigned short*)(sLds + 8192 + (cur) * 8192))
#define SMID     ((unsigned short*)sLds)
#define SB2(cur) ((unsigned short*)(sLds + 16384 + (cur) * 8192))

  const int tid = threadIdx.x;
  const int l = tid & 63, w = tid >> 6;
  const int lr = l & 15, lg = l >> 4;
  const int wr = w >> 2, wc = w & 3;        // phase-1: 2 row x 4 col waves
  const int row = tid >> 3, o4 = tid & 7;   // phase-1 A staging roles

  const int nwg = NTOK / 64 + NUM_CLUSTERS;
  int c, base, nvalid;
  if (!locate(offsets, xcd_swz(blockIdx.x, nwg), 64, c, base, nvalid)) return;

  if (tid < 64) sTok[tid] = perm[base + min(tid, nvalid - 1)];
  LGKM0();
  SBAR();

  const unsigned short* w1base = W1til + (size_t)c * 131072;  // 32 x 4096 shorts
  const unsigned short* wlin   = W2lin + (size_t)c * 131072;  // 32 x 4096 shorts
  const float* hrow = h + (long)sTok[row] * HIDDEN + o4 * 4;

  // ---------------- phase 1 prologue ----------------
  float4 vaA, vaB;
  vaA = *(const float4*)(hrow);
  SCB();
  gload16(w1base + tid * 8, SB1(0) + tid * 8);
  SCB();
  vaB = *(const float4*)(hrow + 32);
  SCB();
  *(bf16x4*)&SA(0)[SWZS(row, row * 32 + o4 * 4)] = pack4(vaA);
  LGKM0();
  VMW(1);          // drain B(0); leave A(1)
  SBAR();

  f32x4 acc[2][2];
  #pragma unroll
  for (int i = 0; i < 2; ++i)
    #pragma unroll
    for (int j = 0; j < 2; ++j) { f32x4 z = {0.f, 0.f, 0.f, 0.f}; acc[i][j] = z; }

  // ---------------- phase 1 main loop (32 K-steps) ----------------
  #pragma unroll
  for (int t = 0; t < 32; ++t) {
    const int cur = t & 1;
    if (t < 31) {
      gload16(w1base + (t + 1) * 4096 + tid * 8, SB1(cur ^ 1) + tid * 8);
      SCB();
    }
    if (t < 30) {
      if (t & 1) vaB = *(const float4*)(hrow + (t + 2) * 32);
      else       vaA = *(const float4*)(hrow + (t + 2) * 32);
      SCB();
    }
    {
      bf16x8 af[2], bfr[2];
      #pragma unroll
      for (int mf = 0; mf < 2; ++mf) {
        const int m = wr * 32 + mf * 16 + lr;
        af[mf] = *(const bf16x8*)&SA(cur)[SWZS(m, m * 32 + lg * 8)];
      }
      #pragma unroll
      for (int nf = 0; nf < 2; ++nf) {
        const int rn = wc * 32 + nf * 16 + lr;
        bfr[nf] = *(const bf16x8*)&SB1(cur)[SWZS(rn, rn * 32 + lg * 8)];
      }
      #pragma unroll
      for (int mf = 0; mf < 2; ++mf)
        #pragma unroll
        for (int nf = 0; nf < 2; ++nf)
          acc[mf][nf] = __builtin_amdgcn_mfma_f32_16x16x32_bf16(
              af[mf], bfr[nf], acc[mf][nf], 0, 0, 0);
    }
    if (t < 31) {
      // stage A(t+1): pack auto-wait leaves {B(t+1), A(t+2)} in flight
      const float4 src = ((t + 1) & 1) ? vaB : vaA;
      *(bf16x4*)&SA(cur ^ 1)[SWZS(row, row * 32 + o4 * 4)] = pack4(src);
      if (t < 30) { VMW(1); } else { VMW(0); }   // drain B(t+1)
      LGKM0();
      SBAR();
    }
  }

  // ---------------- transition ----------------
  SBAR();   // all waves done with phase-1 LDS (sA[1], sB1[1] at t=31)
  gload16(wlin + tid * 8, SB2(0) + tid * 8);   // phase-2 B(0) -> [16K,24K)
  SCB();

  {  // gelu(acc + b1) -> sMid (overwrites [0,16K))
    float b1v[2];
    #pragma unroll
    for (int nf = 0; nf < 2; ++nf) b1v[nf] = b1g[c * BOT + wc * 32 + nf * 16 + lr];
    #pragma unroll
    for (int mf = 0; mf < 2; ++mf) {
      #pragma unroll
      for (int nf = 0; nf < 2; ++nf) {
        #pragma unroll
        for (int r = 0; r < 4; ++r) {
          float x = acc[mf][nf][r] + b1v[nf];
          float g = 0.5f * x * (1.0f + erff(x * 0.70710678118654752f));
          const int m = wr * 32 + mf * 16 + lg * 4 + r;
          const int n = wc * 32 + nf * 16 + lr;
          SMID[SWZS(m, m * 128 + n)] = f2bf(g);
        }
      }
    }
  }
  LGKM0();
  VMW(0);   // B(0) landed
  SBAR();   // sMid visible

  // ---------------- phase 2 (32 chunks x 32 cols) ----------------
  const int wrow = (w & 3) * 16;   // wave's 16-token row block
  const int ch = w >> 2;           // 16-col half of each 32-col chunk

  bf16x8 ma[4];
  {
    const int mrow = wrow + lr;
    #pragma unroll
    for (int kk = 0; kk < 4; ++kk)
      ma[kk] = *(const bf16x8*)&SMID[SWZS(mrow, mrow * 128 + kk * 32 + lg * 8)];
  }

  const float* hr[4];
  float* orp[4];
  #pragma unroll
  for (int r = 0; r < 4; ++r) {
    const long tk = (long)sTok[wrow + lg * 4 + r] * HIDDEN;
    hr[r] = h + tk;
    orp[r] = out + tk;
  }
  const float* b2c = b2g + c * HIDDEN;

  for (int nc = 0; nc < 32; ++nc) {
    const int cur = nc & 1;
    const int cb = nc * 32 + ch * 16;
    // residual/bias for THIS chunk, issued before B(nc+1)
    float hv[4], bv;
    #pragma unroll
    for (int r = 0; r < 4; ++r) hv[r] = hr[r][cb + lr];
    bv = b2c[cb + lr];
    SCB();
    if (nc < 31) {
      gload16(wlin + (nc + 1) * 4096 + tid * 8, SB2(cur ^ 1) + tid * 8);
      SCB();
    }

    f32x4 a2 = {0.f, 0.f, 0.f, 0.f};
    #pragma unroll
    for (int kk = 0; kk < 4; ++kk) {
      const bf16x8 bf = *(const bf16x8*)&SB2(cur)[(kk * 2 + ch) * 512 + l * 8];
      a2 = __builtin_amdgcn_mfma_f32_16x16x32_bf16(ma[kk], bf, a2, 0, 0, 0);
    }

    // direct scalar epilogue; hv consumption auto-waits vmcnt(1), leaving
    // B(nc+1) in flight. Unconditional clamped stores (duplicate-exact).
    #pragma unroll
    for (int r = 0; r < 4; ++r)
      orp[r][cb + lr] = a2[r] + hv[r] + bv;

    if (nc < 31) {
      VMW(4);   // drain B(nc+1); the 4 stores stay in flight
      SBAR();   // all waves done reading SB2(cur)
    }
  }
#undef SA
#undef SB1
#undef SMID
#undef SB2
}

// ---------------- fallback fused kernel (ws too small): TM=128 ----------------
#define FSWZ(row, sidx) ((sidx) ^ (((row) & 7) << 3))

__global__ __launch_bounds__(256, 2) void k_fused(
    const float* __restrict__ h, const float* __restrict__ b1g,
    const float* __restrict__ b2g, const unsigned short* __restrict__ W1til,
    const unsigned short* __restrict__ W2til, const int* __restrict__ offsets,
    const int* __restrict__ perm, float* __restrict__ out) {

  __shared__ __align__(16) unsigned short sAB[16384];
  __shared__ __align__(16) unsigned short sMid[16384];
  __shared__ int sTok[128];

  const int tid = threadIdx.x;
  const int l = tid & 63, w = tid >> 6;
  const int wr = w >> 1, wc = w & 1;
  const int lr = l & 15, lg = l >> 4;

  int c, base, nvalid;
  if (!locate(offsets, blockIdx.x, 128, c, base, nvalid)) return;

  if (tid < 128) sTok[tid] = perm[base + min(tid, nvalid - 1)];
  __syncthreads();

  const unsigned short* w1base = W1til + (size_t)c * 16 * 8192;
  const unsigned short* w2base = W2til + (size_t)c * 16 * 8192;

  const int arow = tid >> 1, ahalf = tid & 1;
  const long htok = (long)sTok[arow] * HIDDEN;

  f32x4 acc[4][4];
  #pragma unroll
  for (int i = 0; i < 4; ++i)
    #pragma unroll
    for (int j = 0; j < 4; ++j) { f32x4 z = {0.f, 0.f, 0.f, 0.f}; acc[i][j] = z; }

  for (int ks = 0; ks < 16; ++ks) {
    __syncthreads();
    const unsigned short* w1s = w1base + ks * 8192;
    #pragma unroll
    for (int j = 0; j < 4; ++j)
      gload16(w1s + j * 2048 + tid * 8, &sAB[8192 + j * 2048 + tid * 8]);
    {
      const float* hp = h + htok + ks * 64 + ahalf * 32;
      float4 v0 = *(const float4*)(hp + 0),  v1 = *(const float4*)(hp + 4);
      float4 v2 = *(const float4*)(hp + 8),  v3 = *(const float4*)(hp + 12);
      float4 v4 = *(const float4*)(hp + 16), v5 = *(const float4*)(hp + 20);
      float4 v6 = *(const float4*)(hp + 24), v7 = *(const float4*)(hp + 28);
      const int sb = arow * 64 + ahalf * 32;
      *(bf16x8*)&sAB[FSWZ(arow, sb + 0)]  = pack8(v0, v1);
      *(bf16x8*)&sAB[FSWZ(arow, sb + 8)]  = pack8(v2, v3);
      *(bf16x8*)&sAB[FSWZ(arow, sb + 16)] = pack8(v4, v5);
      *(bf16x8*)&sAB[FSWZ(arow, sb + 24)] = pack8(v6, v7);
    }
    __syncthreads();
    #pragma unroll
    for (int kk = 0; kk < 2; ++kk) {
      bf16x8 af[4], bfr[4];
      #pragma unroll
      for (int mf = 0; mf < 4; ++mf) {
        const int rw = wr * 64 + mf * 16 + lr;
        af[mf] = *(const bf16x8*)&sAB[FSWZ(rw, rw * 64 + kk * 32 + lg * 8)];
      }
      #pragma unroll
      for (int nf = 0; nf < 4; ++nf) {
        const int rn = wc * 64 + nf * 16 + lr;
        bfr[nf] = *(const bf16x8*)&sAB[8192 + FSWZ(rn, rn * 64 + kk * 32 + lg * 8)];
      }
      #pragma unroll
      for (int mf = 0; mf < 4; ++mf)
        #pragma unroll
        for (int nf = 0; nf < 4; ++nf)
          acc[mf][nf] = __builtin_amdgcn_mfma_f32_16x16x32_bf16(af[mf], bfr[nf], acc[mf][nf], 0, 0, 0);
    }
  }

  float b1v[4];
  #pragma unroll
  for (int nf = 0; nf < 4; ++nf) b1v[nf] = b1g[c * BOT + wc * 64 + nf * 16 + lr];
  #pragma unroll
  for (int mf = 0; mf < 4; ++mf)
    #pragma unroll
    for (int nf = 0; nf < 4; ++nf)
      #pragma unroll
      for (int r = 0; r < 4; ++r) {
        float x = acc[mf][nf][r] + b1v[nf];
        float g = 0.5f * x * (1.0f + erff(x * 0.70710678118654752f));
        const int m = wr * 64 + mf * 16 + lg * 4 + r;
        const int n = wc * 64 + nf * 16 + lr;
        sMid[FSWZ(m, m * 128 + n)] = f2bf(g);
      }

  for (int nc = 0; nc < 16; ++nc) {
    __syncthreads();
    #pragma unroll
    for (int j = 0; j < 4; ++j)
      gload16(w2base + nc * 8192 + j * 2048 + tid * 8, &sAB[j * 2048 + tid * 8]);
    __syncthreads();

    f32x4 a2[4][2];
    #pragma unroll
    for (int i = 0; i < 4; ++i)
      #pragma unroll
      for (int j = 0; j < 2; ++j) { f32x4 z = {0.f, 0.f, 0.f, 0.f}; a2[i][j] = z; }

    #pragma unroll
    for (int kk = 0; kk < 4; ++kk) {
      bf16x8 af[4], bfr[2];
      #pragma unroll
      for (int mf = 0; mf < 4; ++mf) {
        const int m = wr * 64 + mf * 16 + lr;
        af[mf] = *(const bf16x8*)&sMid[FSWZ(m, m * 128 + kk * 32 + lg * 8)];
      }
      #pragma unroll
      for (int nf = 0; nf < 2; ++nf) {
        const int rn = wc * 32 + nf * 16 + lr;
        bfr[nf] = *(const bf16x8*)&sAB[FSWZ(rn, rn * 128 + kk * 32 + lg * 8)];
      }
      #pragma unroll
      for (int mf = 0; mf < 4; ++mf)
        #pragma unroll
        for (int nf = 0; nf < 2; ++nf)
          a2[mf][nf] = __builtin_amdgcn_mfma_f32_16x16x32_bf16(af[mf], bfr[nf], a2[mf][nf], 0, 0, 0);
    }

    #pragma unroll
    for (int nf = 0; nf < 2; ++nf) {
      const int nn = nc * 64 + wc * 32 + nf * 16 + lr;
      const float b2v = b2g[c * HIDDEN + nn];
      #pragma unroll
      for (int mf = 0; mf < 4; ++mf)
        #pragma unroll
        for (int r = 0; r < 4; ++r) {
          const int m = wr * 64 + mf * 16 + lg * 4 + r;
          if (m < nvalid) {
            const long tk = (long)sTok[m] * HIDDEN;
            out[tk + nn] = h[tk + nn] + a2[mf][nf][r] + b2v;
          }
        }
    }
  }
}

// ---------------- launcher ----------------
extern "C" void kernel_launch(void* const* d_in, const int* in_sizes, int n_in,
                              void* d_out, int out_size, void* d_ws, size_t ws_size,
                              hipStream_t stream) {
  const float* h   = (const float*)d_in[0];
  const int*   ids = (const int*)d_in[1];
  const float* W1  = (const float*)d_in[2];
  const float* b1  = (const float*)d_in[3];
  const float* W2  = (const float*)d_in[4];
  const float* b2  = (const float*)d_in[5];
  float* out = (float*)d_out;

  char* ws = (char*)d_ws;
  int* counts  = (int*)ws;            // 16 ints
  int* cursor  = (int*)(ws + 64);     // 16 ints
  int* offsets = (int*)(ws + 128);    // 17 ints
  int* perm    = (int*)(ws + 256);    // 65536 ints, ends at 262400
  unsigned short* W1buf = (unsigned short*)(ws + 262400);             // 4 MB
  unsigned short* W2buf = W1buf + (size_t)16 * 16 * 8192;             // 4 MB
  const size_t need = 262400 + 2 * (size_t)16 * 16 * 8192 * 2;

  k_zero<<<1, 64, 0, stream>>>(counts);
  k_hist<<<256, 256, 0, stream>>>(ids, counts);
  k_scan<<<1, 64, 0, stream>>>(counts, offsets, cursor);
  k_scatter<<<NTOK / 256, 256, 0, stream>>>(ids, cursor, perm);

  if (ws_size >= need) {
    k_w1til32<<<1024, 256, 0, stream>>>(W1, W1buf);
    k_w2lin32<<<1024, 256, 0, stream>>>(W2, W2buf);
    const int nwg = NTOK / 64 + NUM_CLUSTERS;
    k_fuse<<<nwg, 512, 0, stream>>>(h, b1, b2, W1buf, W2buf, offsets, perm, out);
  } else {
    k_w1til<<<1024, 256, 0, stream>>>(W1, W1buf);
    k_w2til<<<1024, 256, 0, stream>>>(W2, W2buf);
    k_fused<<<NTOK / 128 + NUM_CLUSTERS, 256, 0, stream>>>(
        h, b1, b2, W1buf, W2buf, offsets, perm, out);
  }
}